// Round 3
// baseline (269.516 us; speedup 1.0000x reference)
//
#include <hip/hip_runtime.h>

typedef _Float16 f16x8 __attribute__((ext_vector_type(8)));
typedef float    f32x4 __attribute__((ext_vector_type(4)));

#define N_ROWS 8192
#define DIM 64
#define EPS 1e-8f
#define LOG2E 1.4426950408889634f
#define SHIFT 64.0f                      // exp terms scaled by 2^64
#define SHIFT_LN 44.361419555836499802f  // 64 * ln(2)
#define TILE_I 256                       // i-tile (4 waves x 64 rows, mt=4)
#define TILE_J 128                       // j-chunk
#define NTJ (TILE_J / 16)                // 8 j-subtiles per block
#define NBI (N_ROWS / TILE_I)            // 32 i-tiles
#define TB (NBI * (NBI + 1))             // 1056 blocks: per bi, bj=0..2bi+1

// last-block counter for the fused finalization (reset by snn_prep each iter)
__device__ unsigned int g_ctr;

// ws: top[8192] | bot[8192] | sq[8192] (f32) | xh[8192*64] | xl[8192*64] (f16)

// fused: zero top/bot/out/ctr + f16 split + row norms. one wave per row.
__global__ void snn_prep(const float* __restrict__ x, _Float16* __restrict__ xh,
                         _Float16* __restrict__ xl, float* __restrict__ sq,
                         float* __restrict__ top, float* __restrict__ bot,
                         float* __restrict__ out) {
    const int gt = blockIdx.x * 256 + threadIdx.x;
    if (gt < N_ROWS) { top[gt] = 0.0f; bot[gt] = 0.0f; }
    if (gt == 0) { out[0] = 0.0f; g_ctr = 0u; }
    const int row = gt >> 6, lane = threadIdx.x & 63;
    float v = x[row * DIM + lane];
    _Float16 h = (_Float16)v;
    _Float16 l = (_Float16)(v - (float)h);
    xh[row * DIM + lane] = h;
    xl[row * DIM + lane] = l;
    float s = v * v;
    #pragma unroll
    for (int off = 32; off > 0; off >>= 1) s += __shfl_xor(s, off, 64);
    if (lane == 0) sq[row] = s;
}

// Symmetric triangular pass, 256x128 tiles (see round-2 comments), plus:
//  - fully-unrolled nt loop with depth-1 B-fragment software pipeline
//    (round-2 post-mortem: ~7.5K stall cycles/nt of un-hidden B-load latency
//    at ~2 resident blocks/CU; prefetch covers it under the MFMA+epilogue)
//  - raw v_exp_f32 via __builtin_amdgcn_exp2f (no OCML fixup wrapper)
//  - fused finalization: last block computes the loss (saves a launch+gap
//    of the constant ~54us non-mfma component)
__global__ __launch_bounds__(256, 2) void snn_mfma(
    const _Float16* __restrict__ xh, const _Float16* __restrict__ xl,
    const float* __restrict__ sq, const int* __restrict__ y,
    const float* __restrict__ w,
    float* __restrict__ top, float* __restrict__ bot,
    float* __restrict__ out)
{
    __shared__ float s_sqj[TILE_J];
    __shared__ int   s_yj[TILE_J];
    __shared__ float s_jt[4][TILE_J];  // per-wave col-side top (no atomics)
    __shared__ float s_jb[4][TILE_J];  // per-wave col-side bot
    __shared__ bool  s_last;
    __shared__ float s_red[4];

    // bid -> (bi, bj): cumulative blocks before bi is bi*(bi+1)
    const int bid = blockIdx.x;
    int bi = (int)((sqrtf(4.0f * (float)bid + 1.0f) - 1.0f) * 0.5f);
    while ((bi + 1) * (bi + 2) <= bid) ++bi;   // fp guards
    while (bi * (bi + 1) > bid) --bi;
    const int bj = bid - bi * (bi + 1);
    const bool diag = (bj >= 2 * bi);
    const int I0 = bi * TILE_I, J0 = bj * TILE_J;

    const int tid = threadIdx.x, wv = tid >> 6, lane = tid & 63;
    const int mrow = lane & 15, kq = lane >> 4;

    if (tid < TILE_J) {
        s_sqj[tid] = sq[J0 + tid];
        s_yj[tid]  = y[J0 + tid];
    }
    __syncthreads();

    const int iw = I0 + wv * 64;   // this wave's first i-row

    // A fragments resident for the block lifetime (64 VGPRs)
    f16x8 ah[4][2], al[4][2];
    #pragma unroll
    for (int mt = 0; mt < 4; mt++)
        #pragma unroll
        for (int kc = 0; kc < 2; kc++) {
            int a = (iw + mt * 16 + mrow) * DIM + kc * 32 + kq * 8;
            ah[mt][kc] = *(const f16x8*)(xh + a);
            al[mt][kc] = *(const f16x8*)(xl + a);
        }

    // per-slot row metadata: i = iw + mt*16 + kq*4 + rr ; labels packed 4/VGPR
    float sqi[4][4]; int ypack[4];
    #pragma unroll
    for (int mt = 0; mt < 4; mt++) {
        int yp = 0;
        #pragma unroll
        for (int rr = 0; rr < 4; rr++) {
            int i = iw + mt * 16 + kq * 4 + rr;
            sqi[mt][rr] = sq[i];
            yp |= (y[i] & 255) << (8 * rr);
        }
        ypack[mt] = yp;
    }

    float ts[4][4], bs[4][4];
    #pragma unroll
    for (int mt = 0; mt < 4; mt++)
        #pragma unroll
        for (int rr = 0; rr < 4; rr++) { ts[mt][rr] = 0.0f; bs[mt][rr] = 0.0f; }

    const float c1 = -w[0] * LOG2E;

#define DO_MFMA()                                                                \
    f32x4 acc[4];                                                                \
    _Pragma("unroll")                                                            \
    for (int mt = 0; mt < 4; mt++) acc[mt] = (f32x4){0.f, 0.f, 0.f, 0.f};        \
    _Pragma("unroll")                                                            \
    for (int mt = 0; mt < 4; mt++)                                               \
        acc[mt] = __builtin_amdgcn_mfma_f32_16x16x32_f16(ah[mt][0], cbh0, acc[mt], 0, 0, 0); \
    _Pragma("unroll")                                                            \
    for (int mt = 0; mt < 4; mt++)                                               \
        acc[mt] = __builtin_amdgcn_mfma_f32_16x16x32_f16(ah[mt][1], cbh1, acc[mt], 0, 0, 0); \
    _Pragma("unroll")                                                            \
    for (int mt = 0; mt < 4; mt++)                                               \
        acc[mt] = __builtin_amdgcn_mfma_f32_16x16x32_f16(ah[mt][0], cbl0, acc[mt], 0, 0, 0); \
    _Pragma("unroll")                                                            \
    for (int mt = 0; mt < 4; mt++)                                               \
        acc[mt] = __builtin_amdgcn_mfma_f32_16x16x32_f16(ah[mt][1], cbl1, acc[mt], 0, 0, 0); \
    _Pragma("unroll")                                                            \
    for (int mt = 0; mt < 4; mt++)                                               \
        acc[mt] = __builtin_amdgcn_mfma_f32_16x16x32_f16(al[mt][0], cbh0, acc[mt], 0, 0, 0); \
    _Pragma("unroll")                                                            \
    for (int mt = 0; mt < 4; mt++)                                               \
        acc[mt] = __builtin_amdgcn_mfma_f32_16x16x32_f16(al[mt][1], cbh1, acc[mt], 0, 0, 0);

    if (!diag) {
        // strictly below diagonal: i != j guaranteed; accumulate both sides.
        // depth-1 pipelined, fully unrolled: issue nt+1 loads before nt compute.
        int boff0 = (J0 + mrow) * DIM + kq * 8;
        f16x8 cbh0 = *(const f16x8*)(xh + boff0);
        f16x8 cbh1 = *(const f16x8*)(xh + boff0 + 32);
        f16x8 cbl0 = *(const f16x8*)(xl + boff0);
        f16x8 cbl1 = *(const f16x8*)(xl + boff0 + 32);
        #pragma unroll
        for (int nt = 0; nt < NTJ; nt++) {
            f16x8 nbh0, nbh1, nbl0, nbl1;
            if (nt + 1 < NTJ) {
                int nb = (J0 + (nt + 1) * 16 + mrow) * DIM + kq * 8;
                nbh0 = *(const f16x8*)(xh + nb);
                nbh1 = *(const f16x8*)(xh + nb + 32);
                nbl0 = *(const f16x8*)(xl + nb);
                nbl1 = *(const f16x8*)(xl + nb + 32);
            }
            const float sqj = s_sqj[nt * 16 + mrow];
            const int   yj  = s_yj[nt * 16 + mrow];
            DO_MFMA()
            float jt = 0.0f, jb = 0.0f;
            #pragma unroll
            for (int mt = 0; mt < 4; mt++)
                #pragma unroll
                for (int rr = 0; rr < 4; rr++) {
                    float d2 = fmaf(-2.0f, acc[mt][rr], sqi[mt][rr] + sqj);
                    d2 = fmaxf(d2, 0.0f);
                    float dist = __builtin_amdgcn_sqrtf(d2);
                    float e2 = __builtin_amdgcn_exp2f(fmaf(c1, dist, SHIFT));
                    float e2t = (yj == ((ypack[mt] >> (8 * rr)) & 255)) ? e2 : 0.0f;
                    ts[mt][rr] += e2t;
                    bs[mt][rr] += e2;
                    jt += e2t;
                    jb += e2;
                }
            // col-side: reduce over the 4 kq groups; each (wv,col) written once
            jt += __shfl_xor(jt, 16, 64); jt += __shfl_xor(jt, 32, 64);
            jb += __shfl_xor(jb, 16, 64); jb += __shfl_xor(jb, 32, 64);
            if (kq == 0) {
                s_jt[wv][nt * 16 + mrow] = jt;
                s_jb[wv][nt * 16 + mrow] = jb;
            }
            if (nt + 1 < NTJ) { cbh0 = nbh0; cbh1 = nbh1; cbl0 = nbl0; cbl1 = nbl1; }
        }
    } else {
        // diagonal square half (64/1056 blocks): one-sided, guard i==j.
        // kept un-pipelined to halve I-cache footprint.
        for (int nt = 0; nt < NTJ; nt++) {
            const int jbase = J0 + nt * 16;
            const int boff = (jbase + mrow) * DIM + kq * 8;
            f16x8 cbh0 = *(const f16x8*)(xh + boff);
            f16x8 cbh1 = *(const f16x8*)(xh + boff + 32);
            f16x8 cbl0 = *(const f16x8*)(xl + boff);
            f16x8 cbl1 = *(const f16x8*)(xl + boff + 32);
            const float sqj = s_sqj[nt * 16 + mrow];
            const int   yj  = s_yj[nt * 16 + mrow];
            const int   j   = jbase + mrow;
            DO_MFMA()
            #pragma unroll
            for (int mt = 0; mt < 4; mt++)
                #pragma unroll
                for (int rr = 0; rr < 4; rr++) {
                    int i = iw + mt * 16 + kq * 4 + rr;
                    float d2 = fmaf(-2.0f, acc[mt][rr], sqi[mt][rr] + sqj);
                    d2 = fmaxf(d2, 0.0f);
                    float dist = __builtin_amdgcn_sqrtf(d2);
                    float e2 = __builtin_amdgcn_exp2f(fmaf(c1, dist, SHIFT));
                    bool offd = (i != j);
                    bool same = offd && (yj == ((ypack[mt] >> (8 * rr)) & 255));
                    bs[mt][rr] += offd ? e2 : 0.0f;
                    ts[mt][rr] += same ? e2 : 0.0f;
                }
        }
    }
#undef DO_MFMA

    // row-side: reduce across the 16 mrow lanes sharing each row, one atomic/row
    #pragma unroll
    for (int mt = 0; mt < 4; mt++)
        #pragma unroll
        for (int rr = 0; rr < 4; rr++) {
            float tv = ts[mt][rr], bv = bs[mt][rr];
            #pragma unroll
            for (int off = 1; off < 16; off <<= 1) {
                tv += __shfl_xor(tv, off, 64);
                bv += __shfl_xor(bv, off, 64);
            }
            if (mrow == 0) {
                int i = iw + mt * 16 + kq * 4 + rr;
                atomicAdd(&top[i], tv);
                atomicAdd(&bot[i], bv);
            }
        }

    // col-side drain: sum the 4 per-wave slices, one atomic per column
    if (!diag) {
        __syncthreads();
        if (tid < TILE_J) {
            float t = s_jt[0][tid] + s_jt[1][tid] + s_jt[2][tid] + s_jt[3][tid];
            float b = s_jb[0][tid] + s_jb[1][tid] + s_jb[2][tid] + s_jb[3][tid];
            atomicAdd(&top[J0 + tid], t);
            atomicAdd(&bot[J0 + tid], b);
        }
    }

    // fused finalization: last block to finish computes the loss
    __threadfence();
    __syncthreads();
    if (tid == 0) s_last = (atomicAdd(&g_ctr, 1u) == TB - 1);
    __syncthreads();
    if (s_last) {
        float acc = 0.0f;
        for (int r2 = tid; r2 < N_ROWS; r2 += 256) {
            float t = __hip_atomic_load(&top[r2], __ATOMIC_RELAXED, __HIP_MEMORY_SCOPE_AGENT);
            float b = __hip_atomic_load(&bot[r2], __ATOMIC_RELAXED, __HIP_MEMORY_SCOPE_AGENT);
            acc += (logf(t) - SHIFT_LN) - logf(b * 0x1p-64f + EPS);
        }
        #pragma unroll
        for (int off = 32; off > 0; off >>= 1) acc += __shfl_xor(acc, off, 64);
        if ((tid & 63) == 0) s_red[tid >> 6] = acc;
        __syncthreads();
        if (tid == 0)
            out[0] = -(s_red[0] + s_red[1] + s_red[2] + s_red[3]) / (float)N_ROWS;
    }
}

extern "C" void kernel_launch(void* const* d_in, const int* in_sizes, int n_in,
                              void* d_out, int out_size, void* d_ws, size_t ws_size,
                              hipStream_t stream) {
    const float* x = (const float*)d_in[0];
    const int*   y = (const int*)d_in[1];
    const float* w = (const float*)d_in[2];
    float* out = (float*)d_out;

    float* ws  = (float*)d_ws;
    float* top = ws;
    float* bot = ws + N_ROWS;
    float* sq  = ws + 2 * N_ROWS;
    _Float16* xh = (_Float16*)(ws + 3 * N_ROWS);
    _Float16* xl = xh + (size_t)N_ROWS * DIM;

    snn_prep<<<N_ROWS / 4, 256, 0, stream>>>(x, xh, xl, sq, top, bot, out);
    snn_mfma<<<TB, 256, 0, stream>>>(xh, xl, sq, y, w, top, bot, out);
}

// Round 5
// 174.957 us; speedup vs baseline: 1.5405x; 1.5405x over previous
//
#include <hip/hip_runtime.h>

typedef _Float16 f16x8 __attribute__((ext_vector_type(8)));
typedef float    f32x4 __attribute__((ext_vector_type(4)));

#define N_ROWS 8192
#define DIM 64
#define EPS 1e-8f
#define LOG2E 1.4426950408889634f
#define SHIFT 64.0f                      // exp terms scaled by 2^64
#define SHIFT_LN 44.361419555836499802f  // 64 * ln(2)
#define TILE_I 256                       // i-tile (4 waves x 64 rows, mt=4)
#define TILE_J 128                       // j-chunk
#define NTJ (TILE_J / 16)                // 8 j-subtiles per block
#define NBI (N_ROWS / TILE_I)            // 32 i-tiles
#define TB (NBI * (NBI + 1))             // 1056 blocks: per bi, bj=0..2bi+1

// last-block counter for the fused finalization (reset by snn_prep each iter)
__device__ unsigned int g_ctr;

// ws: top[8192] | bot[8192] | sq[8192] (f32) | xh[8192*64] | xl[8192*64] (f16)

// fused: zero top/bot/out/ctr + f16 split + row norms. one wave per row.
__global__ void snn_prep(const float* __restrict__ x, _Float16* __restrict__ xh,
                         _Float16* __restrict__ xl, float* __restrict__ sq,
                         float* __restrict__ top, float* __restrict__ bot,
                         float* __restrict__ out) {
    const int gt = blockIdx.x * 256 + threadIdx.x;
    if (gt < N_ROWS) { top[gt] = 0.0f; bot[gt] = 0.0f; }
    if (gt == 0) { out[0] = 0.0f; g_ctr = 0u; }
    const int row = gt >> 6, lane = threadIdx.x & 63;
    float v = x[row * DIM + lane];
    _Float16 h = (_Float16)v;
    _Float16 l = (_Float16)(v - (float)h);
    xh[row * DIM + lane] = h;
    xl[row * DIM + lane] = l;
    float s = v * v;
    #pragma unroll
    for (int off = 32; off > 0; off >>= 1) s += __shfl_xor(s, off, 64);
    if (lane == 0) sq[row] = s;
}

// Symmetric triangular pass, 256x128 tiles (round-2 structure), plus:
//  - depth-1 B-fragment prefetch in a DYNAMIC loop with `#pragma unroll 2`
//    (round-3 post-mortem: full unroll let the scheduler hoist all 8 tiles'
//    loads -> 139 MB scratch spill. unroll 2 bounds live B-state to <=3
//    tiles = 48 VGPRs and lets the allocator ping-pong without movs)
//  - raw v_exp_f32 via __builtin_amdgcn_exp2f (no OCML fixup wrapper)
//  - fused finalization (last block computes the loss)
// (round-4 bench was an infra failure — container acquisition; resubmitted)
__global__ __launch_bounds__(256, 2) void snn_mfma(
    const _Float16* __restrict__ xh, const _Float16* __restrict__ xl,
    const float* __restrict__ sq, const int* __restrict__ y,
    const float* __restrict__ w,
    float* __restrict__ top, float* __restrict__ bot,
    float* __restrict__ out)
{
    __shared__ float s_sqj[TILE_J];
    __shared__ int   s_yj[TILE_J];
    __shared__ float s_jt[4][TILE_J];  // per-wave col-side top (no atomics)
    __shared__ float s_jb[4][TILE_J];  // per-wave col-side bot
    __shared__ bool  s_last;
    __shared__ float s_red[4];

    // bid -> (bi, bj): cumulative blocks before bi is bi*(bi+1)
    const int bid = blockIdx.x;
    int bi = (int)((sqrtf(4.0f * (float)bid + 1.0f) - 1.0f) * 0.5f);
    while ((bi + 1) * (bi + 2) <= bid) ++bi;   // fp guards
    while (bi * (bi + 1) > bid) --bi;
    const int bj = bid - bi * (bi + 1);
    const bool diag = (bj >= 2 * bi);
    const int I0 = bi * TILE_I, J0 = bj * TILE_J;

    const int tid = threadIdx.x, wv = tid >> 6, lane = tid & 63;
    const int mrow = lane & 15, kq = lane >> 4;

    if (tid < TILE_J) {
        s_sqj[tid] = sq[J0 + tid];
        s_yj[tid]  = y[J0 + tid];
    }
    __syncthreads();

    const int iw = I0 + wv * 64;   // this wave's first i-row

    // A fragments resident for the block lifetime
    f16x8 ah[4][2], al[4][2];
    #pragma unroll
    for (int mt = 0; mt < 4; mt++)
        #pragma unroll
        for (int kc = 0; kc < 2; kc++) {
            int a = (iw + mt * 16 + mrow) * DIM + kc * 32 + kq * 8;
            ah[mt][kc] = *(const f16x8*)(xh + a);
            al[mt][kc] = *(const f16x8*)(xl + a);
        }

    // per-slot row metadata: i = iw + mt*16 + kq*4 + rr ; labels packed 4/VGPR
    float sqi[4][4]; int ypack[4];
    #pragma unroll
    for (int mt = 0; mt < 4; mt++) {
        int yp = 0;
        #pragma unroll
        for (int rr = 0; rr < 4; rr++) {
            int i = iw + mt * 16 + kq * 4 + rr;
            sqi[mt][rr] = sq[i];
            yp |= (y[i] & 255) << (8 * rr);
        }
        ypack[mt] = yp;
    }

    float ts[4][4], bs[4][4];
    #pragma unroll
    for (int mt = 0; mt < 4; mt++)
        #pragma unroll
        for (int rr = 0; rr < 4; rr++) { ts[mt][rr] = 0.0f; bs[mt][rr] = 0.0f; }

    const float c1 = -w[0] * LOG2E;

#define DO_MFMA()                                                                \
    f32x4 acc[4];                                                                \
    _Pragma("unroll")                                                            \
    for (int mt = 0; mt < 4; mt++) acc[mt] = (f32x4){0.f, 0.f, 0.f, 0.f};        \
    _Pragma("unroll")                                                            \
    for (int mt = 0; mt < 4; mt++)                                               \
        acc[mt] = __builtin_amdgcn_mfma_f32_16x16x32_f16(ah[mt][0], cbh0, acc[mt], 0, 0, 0); \
    _Pragma("unroll")                                                            \
    for (int mt = 0; mt < 4; mt++)                                               \
        acc[mt] = __builtin_amdgcn_mfma_f32_16x16x32_f16(ah[mt][1], cbh1, acc[mt], 0, 0, 0); \
    _Pragma("unroll")                                                            \
    for (int mt = 0; mt < 4; mt++)                                               \
        acc[mt] = __builtin_amdgcn_mfma_f32_16x16x32_f16(ah[mt][0], cbl0, acc[mt], 0, 0, 0); \
    _Pragma("unroll")                                                            \
    for (int mt = 0; mt < 4; mt++)                                               \
        acc[mt] = __builtin_amdgcn_mfma_f32_16x16x32_f16(ah[mt][1], cbl1, acc[mt], 0, 0, 0); \
    _Pragma("unroll")                                                            \
    for (int mt = 0; mt < 4; mt++)                                               \
        acc[mt] = __builtin_amdgcn_mfma_f32_16x16x32_f16(al[mt][0], cbh0, acc[mt], 0, 0, 0); \
    _Pragma("unroll")                                                            \
    for (int mt = 0; mt < 4; mt++)                                               \
        acc[mt] = __builtin_amdgcn_mfma_f32_16x16x32_f16(al[mt][1], cbh1, acc[mt], 0, 0, 0);

    if (!diag) {
        // strictly below diagonal: i != j guaranteed; accumulate both sides.
        // depth-1 prefetch, dynamic loop (unroll 2 -> reg ping-pong, no hoist-all)
        int boff0 = (J0 + mrow) * DIM + kq * 8;
        f16x8 cbh0 = *(const f16x8*)(xh + boff0);
        f16x8 cbh1 = *(const f16x8*)(xh + boff0 + 32);
        f16x8 cbl0 = *(const f16x8*)(xl + boff0);
        f16x8 cbl1 = *(const f16x8*)(xl + boff0 + 32);
        #pragma unroll 2
        for (int nt = 0; nt < NTJ; nt++) {
            // unconditional wrapped prefetch (last iter redundantly reloads nt=0:
            // L1-hit, avoids divergence and keeps the loop branch-free)
            const int nb = (J0 + ((nt + 1) & (NTJ - 1)) * 16 + mrow) * DIM + kq * 8;
            f16x8 nbh0 = *(const f16x8*)(xh + nb);
            f16x8 nbh1 = *(const f16x8*)(xh + nb + 32);
            f16x8 nbl0 = *(const f16x8*)(xl + nb);
            f16x8 nbl1 = *(const f16x8*)(xl + nb + 32);
            const float sqj = s_sqj[nt * 16 + mrow];
            const int   yj  = s_yj[nt * 16 + mrow];
            DO_MFMA()
            float jt = 0.0f, jb = 0.0f;
            #pragma unroll
            for (int mt = 0; mt < 4; mt++)
                #pragma unroll
                for (int rr = 0; rr < 4; rr++) {
                    float d2 = fmaf(-2.0f, acc[mt][rr], sqi[mt][rr] + sqj);
                    d2 = fmaxf(d2, 0.0f);
                    float dist = __builtin_amdgcn_sqrtf(d2);
                    float e2 = __builtin_amdgcn_exp2f(fmaf(c1, dist, SHIFT));
                    float e2t = (yj == ((ypack[mt] >> (8 * rr)) & 255)) ? e2 : 0.0f;
                    ts[mt][rr] += e2t;
                    bs[mt][rr] += e2;
                    jt += e2t;
                    jb += e2;
                }
            // col-side: reduce over the 4 kq groups; each (wv,col) written once
            jt += __shfl_xor(jt, 16, 64); jt += __shfl_xor(jt, 32, 64);
            jb += __shfl_xor(jb, 16, 64); jb += __shfl_xor(jb, 32, 64);
            if (kq == 0) {
                s_jt[wv][nt * 16 + mrow] = jt;
                s_jb[wv][nt * 16 + mrow] = jb;
            }
            cbh0 = nbh0; cbh1 = nbh1; cbl0 = nbl0; cbl1 = nbl1;
        }
    } else {
        // diagonal square half (64/1056 blocks): one-sided, guard i==j
        #pragma unroll 1
        for (int nt = 0; nt < NTJ; nt++) {
            const int jbase = J0 + nt * 16;
            const int boff = (jbase + mrow) * DIM + kq * 8;
            f16x8 cbh0 = *(const f16x8*)(xh + boff);
            f16x8 cbh1 = *(const f16x8*)(xh + boff + 32);
            f16x8 cbl0 = *(const f16x8*)(xl + boff);
            f16x8 cbl1 = *(const f16x8*)(xl + boff + 32);
            const float sqj = s_sqj[nt * 16 + mrow];
            const int   yj  = s_yj[nt * 16 + mrow];
            const int   j   = jbase + mrow;
            DO_MFMA()
            #pragma unroll
            for (int mt = 0; mt < 4; mt++)
                #pragma unroll
                for (int rr = 0; rr < 4; rr++) {
                    int i = iw + mt * 16 + kq * 4 + rr;
                    float d2 = fmaf(-2.0f, acc[mt][rr], sqi[mt][rr] + sqj);
                    d2 = fmaxf(d2, 0.0f);
                    float dist = __builtin_amdgcn_sqrtf(d2);
                    float e2 = __builtin_amdgcn_exp2f(fmaf(c1, dist, SHIFT));
                    bool offd = (i != j);
                    bool same = offd && (yj == ((ypack[mt] >> (8 * rr)) & 255));
                    bs[mt][rr] += offd ? e2 : 0.0f;
                    ts[mt][rr] += same ? e2 : 0.0f;
                }
        }
    }
#undef DO_MFMA

    // row-side: reduce across the 16 mrow lanes sharing each row, one atomic/row
    #pragma unroll
    for (int mt = 0; mt < 4; mt++)
        #pragma unroll
        for (int rr = 0; rr < 4; rr++) {
            float tv = ts[mt][rr], bv = bs[mt][rr];
            #pragma unroll
            for (int off = 1; off < 16; off <<= 1) {
                tv += __shfl_xor(tv, off, 64);
                bv += __shfl_xor(bv, off, 64);
            }
            if (mrow == 0) {
                int i = iw + mt * 16 + kq * 4 + rr;
                atomicAdd(&top[i], tv);
                atomicAdd(&bot[i], bv);
            }
        }

    // col-side drain: sum the 4 per-wave slices, one atomic per column
    if (!diag) {
        __syncthreads();
        if (tid < TILE_J) {
            float t = s_jt[0][tid] + s_jt[1][tid] + s_jt[2][tid] + s_jt[3][tid];
            float b = s_jb[0][tid] + s_jb[1][tid] + s_jb[2][tid] + s_jb[3][tid];
            atomicAdd(&top[J0 + tid], t);
            atomicAdd(&bot[J0 + tid], b);
        }
    }

    // fused finalization: last block to finish computes the loss
    __threadfence();
    __syncthreads();
    if (tid == 0) s_last = (atomicAdd(&g_ctr, 1u) == TB - 1);
    __syncthreads();
    if (s_last) {
        float acc = 0.0f;
        for (int r2 = tid; r2 < N_ROWS; r2 += 256) {
            float t = __hip_atomic_load(&top[r2], __ATOMIC_RELAXED, __HIP_MEMORY_SCOPE_AGENT);
            float b = __hip_atomic_load(&bot[r2], __ATOMIC_RELAXED, __HIP_MEMORY_SCOPE_AGENT);
            acc += (logf(t) - SHIFT_LN) - logf(b * 0x1p-64f + EPS);
        }
        #pragma unroll
        for (int off = 32; off > 0; off >>= 1) acc += __shfl_xor(acc, off, 64);
        if ((tid & 63) == 0) s_red[tid >> 6] = acc;
        __syncthreads();
        if (tid == 0)
            out[0] = -(s_red[0] + s_red[1] + s_red[2] + s_red[3]) / (float)N_ROWS;
    }
}

extern "C" void kernel_launch(void* const* d_in, const int* in_sizes, int n_in,
                              void* d_out, int out_size, void* d_ws, size_t ws_size,
                              hipStream_t stream) {
    const float* x = (const float*)d_in[0];
    const int*   y = (const int*)d_in[1];
    const float* w = (const float*)d_in[2];
    float* out = (float*)d_out;

    float* ws  = (float*)d_ws;
    float* top = ws;
    float* bot = ws + N_ROWS;
    float* sq  = ws + 2 * N_ROWS;
    _Float16* xh = (_Float16*)(ws + 3 * N_ROWS);
    _Float16* xl = xh + (size_t)N_ROWS * DIM;

    snn_prep<<<N_ROWS / 4, 256, 0, stream>>>(x, xh, xl, sq, top, bot, out);
    snn_mfma<<<TB, 256, 0, stream>>>(xh, xl, sq, y, w, top, bot, out);
}

// Round 6
// 163.535 us; speedup vs baseline: 1.6481x; 1.0698x over previous
//
#include <hip/hip_runtime.h>

typedef _Float16 f16x8 __attribute__((ext_vector_type(8)));
typedef float    f32x4 __attribute__((ext_vector_type(4)));

#define N_ROWS 8192
#define DIM 64
#define EPS 1e-8f
#define LOG2E 1.4426950408889634f
#define SHIFT 64.0f                      // exp terms scaled by 2^64
#define SHIFT_LN 44.361419555836499802f  // 64 * ln(2)
#define TILE_I 256                       // i-tile (4 waves x 64 rows, mt=4)
#define TILE_J 128                       // j-chunk
#define NTJ (TILE_J / 16)                // 8 j-subtiles per block
#define NBI (N_ROWS / TILE_I)            // 32 i-tiles
#define TB (NBI * (NBI + 1))             // 1056 blocks: per bi, bj=0..2bi+1

// last-block counter for the fused finalization (reset by snn_prep each iter)
__device__ unsigned int g_ctr;

// ws: top[8192] | bot[8192] | sq[8192] (f32) | xh[8192*64] | xl[8192*64] (f16)

// fused: zero top/bot/out/ctr + f16 split + row norms. one wave per row.
__global__ void snn_prep(const float* __restrict__ x, _Float16* __restrict__ xh,
                         _Float16* __restrict__ xl, float* __restrict__ sq,
                         float* __restrict__ top, float* __restrict__ bot,
                         float* __restrict__ out) {
    const int gt = blockIdx.x * 256 + threadIdx.x;
    if (gt < N_ROWS) { top[gt] = 0.0f; bot[gt] = 0.0f; }
    if (gt == 0) { out[0] = 0.0f; g_ctr = 0u; }
    const int row = gt >> 6, lane = threadIdx.x & 63;
    float v = x[row * DIM + lane];
    _Float16 h = (_Float16)v;
    _Float16 l = (_Float16)(v - (float)h);
    xh[row * DIM + lane] = h;
    xl[row * DIM + lane] = l;
    float s = v * v;
    #pragma unroll
    for (int off = 32; off > 0; off >>= 1) s += __shfl_xor(s, off, 64);
    if (lane == 0) sq[row] = s;
}

// Symmetric triangular pass, 256x128 tiles (round-2 structure), with the
// whole 128-row j-tile (xh+xl, 32KB) staged to LDS once per block:
//  - removes the ~2.9K cyc/nt of exposed VMEM latency (R2 post-mortem) and
//    the 4x redundant per-wave B-tile fetch; in-loop reads are ds_read_b128
//    which the compiler pipelines with fine lgkmcnt (guide m97)
//  - XOR chunk-swizzle, BOTH sides (write permuted, read permuted): row-major
//    [128][128B] at stride 128B is a 16-way bank conflict for the 16 same-kq
//    lanes; physical chunk = logical chunk ^ (row&7) balances to 8 dwords/bank
//  - loop body back to R2's plain form; R3/R5 manual prefetch arcs are dead
//    (compiler drains vmcnt(0) before MFMA -> serialized; Common-mistake #5)
//  - raw v_exp_f32 + fused last-block finalization kept from R5 (both fine)
__global__ __launch_bounds__(256, 2) void snn_mfma(
    const _Float16* __restrict__ xh, const _Float16* __restrict__ xl,
    const float* __restrict__ sq, const int* __restrict__ y,
    const float* __restrict__ w,
    float* __restrict__ top, float* __restrict__ bot,
    float* __restrict__ out)
{
    __shared__ __align__(16) _Float16 s_bh[TILE_J * DIM];  // 16KB staged xh tile
    __shared__ __align__(16) _Float16 s_bl[TILE_J * DIM];  // 16KB staged xl tile
    __shared__ float s_sqj[TILE_J];
    __shared__ int   s_yj[TILE_J];
    __shared__ float s_jt[4][TILE_J];  // per-wave col-side top (no atomics)
    __shared__ float s_jb[4][TILE_J];  // per-wave col-side bot
    __shared__ bool  s_last;
    __shared__ float s_red[4];

    // bid -> (bi, bj): cumulative blocks before bi is bi*(bi+1)
    const int bid = blockIdx.x;
    int bi = (int)((sqrtf(4.0f * (float)bid + 1.0f) - 1.0f) * 0.5f);
    while ((bi + 1) * (bi + 2) <= bid) ++bi;   // fp guards
    while (bi * (bi + 1) > bid) --bi;
    const int bj = bid - bi * (bi + 1);
    const bool diag = (bj >= 2 * bi);
    const int I0 = bi * TILE_I, J0 = bj * TILE_J;

    const int tid = threadIdx.x, wv = tid >> 6, lane = tid & 63;
    const int mrow = lane & 15, kq = lane >> 4;

    // ---- stage j-tile to LDS with chunk swizzle (involution) ----
    // 16B chunks; tile = 1024 chunks per buffer; 4 rounds x 256 threads.
    // physical chunk p = (m&~7) | ((m&7) ^ ((m>>3)&7))
    {
        const _Float16* gh = xh + (size_t)J0 * DIM;
        const _Float16* gl = xl + (size_t)J0 * DIM;
        #pragma unroll
        for (int c = 0; c < 4; c++) {
            int m = c * 256 + tid;                       // linear global chunk
            int p = (m & ~7) | ((m & 7) ^ ((m >> 3) & 7));
            *(f16x8*)(s_bh + p * 8) = *(const f16x8*)(gh + m * 8);
            *(f16x8*)(s_bl + p * 8) = *(const f16x8*)(gl + m * 8);
        }
    }
    if (tid < TILE_J) {
        s_sqj[tid] = sq[J0 + tid];
        s_yj[tid]  = y[J0 + tid];
    }
    __syncthreads();   // only barrier before the drain: tile is read-only below

    const int iw = I0 + wv * 64;   // this wave's first i-row

    // reader swizzle constants: row = nt*16+mrow, (row&7) == (mrow&7)
    const int swc0 = (kq ^ (mrow & 7)) << 3;   // logical chunk kq   (halves)
    const int swc1 = swc0 ^ 32;                // logical chunk kq+4 (^4 chunks)

    // A fragments resident for the block lifetime
    f16x8 ah[4][2], al[4][2];
    #pragma unroll
    for (int mt = 0; mt < 4; mt++)
        #pragma unroll
        for (int kc = 0; kc < 2; kc++) {
            int a = (iw + mt * 16 + mrow) * DIM + kc * 32 + kq * 8;
            ah[mt][kc] = *(const f16x8*)(xh + a);
            al[mt][kc] = *(const f16x8*)(xl + a);
        }

    // per-slot row metadata: i = iw + mt*16 + kq*4 + rr ; labels packed 4/VGPR
    float sqi[4][4]; int ypack[4];
    #pragma unroll
    for (int mt = 0; mt < 4; mt++) {
        int yp = 0;
        #pragma unroll
        for (int rr = 0; rr < 4; rr++) {
            int i = iw + mt * 16 + kq * 4 + rr;
            sqi[mt][rr] = sq[i];
            yp |= (y[i] & 255) << (8 * rr);
        }
        ypack[mt] = yp;
    }

    float ts[4][4], bs[4][4];
    #pragma unroll
    for (int mt = 0; mt < 4; mt++)
        #pragma unroll
        for (int rr = 0; rr < 4; rr++) { ts[mt][rr] = 0.0f; bs[mt][rr] = 0.0f; }

    const float c1 = -w[0] * LOG2E;

#define LOAD_B_LDS(NT_)                                                          \
    const _Float16* bhp = s_bh + ((NT_) * 16 + mrow) * DIM;                      \
    const _Float16* blp = s_bl + ((NT_) * 16 + mrow) * DIM;                      \
    f16x8 cbh0 = *(const f16x8*)(bhp + swc0);                                    \
    f16x8 cbh1 = *(const f16x8*)(bhp + swc1);                                    \
    f16x8 cbl0 = *(const f16x8*)(blp + swc0);                                    \
    f16x8 cbl1 = *(const f16x8*)(blp + swc1);

#define DO_MFMA()                                                                \
    f32x4 acc[4];                                                                \
    _Pragma("unroll")                                                            \
    for (int mt = 0; mt < 4; mt++) acc[mt] = (f32x4){0.f, 0.f, 0.f, 0.f};        \
    _Pragma("unroll")                                                            \
    for (int mt = 0; mt < 4; mt++)                                               \
        acc[mt] = __builtin_amdgcn_mfma_f32_16x16x32_f16(ah[mt][0], cbh0, acc[mt], 0, 0, 0); \
    _Pragma("unroll")                                                            \
    for (int mt = 0; mt < 4; mt++)                                               \
        acc[mt] = __builtin_amdgcn_mfma_f32_16x16x32_f16(ah[mt][1], cbh1, acc[mt], 0, 0, 0); \
    _Pragma("unroll")                                                            \
    for (int mt = 0; mt < 4; mt++)                                               \
        acc[mt] = __builtin_amdgcn_mfma_f32_16x16x32_f16(ah[mt][0], cbl0, acc[mt], 0, 0, 0); \
    _Pragma("unroll")                                                            \
    for (int mt = 0; mt < 4; mt++)                                               \
        acc[mt] = __builtin_amdgcn_mfma_f32_16x16x32_f16(ah[mt][1], cbl1, acc[mt], 0, 0, 0); \
    _Pragma("unroll")                                                            \
    for (int mt = 0; mt < 4; mt++)                                               \
        acc[mt] = __builtin_amdgcn_mfma_f32_16x16x32_f16(al[mt][0], cbh0, acc[mt], 0, 0, 0); \
    _Pragma("unroll")                                                            \
    for (int mt = 0; mt < 4; mt++)                                               \
        acc[mt] = __builtin_amdgcn_mfma_f32_16x16x32_f16(al[mt][1], cbh1, acc[mt], 0, 0, 0);

    if (!diag) {
        // strictly below diagonal: i != j guaranteed; accumulate both sides
        #pragma unroll 2
        for (int nt = 0; nt < NTJ; nt++) {
            LOAD_B_LDS(nt)
            const float sqj = s_sqj[nt * 16 + mrow];
            const int   yj  = s_yj[nt * 16 + mrow];
            DO_MFMA()
            float jt = 0.0f, jb = 0.0f;
            #pragma unroll
            for (int mt = 0; mt < 4; mt++)
                #pragma unroll
                for (int rr = 0; rr < 4; rr++) {
                    float d2 = fmaf(-2.0f, acc[mt][rr], sqi[mt][rr] + sqj);
                    d2 = fmaxf(d2, 0.0f);
                    float dist = __builtin_amdgcn_sqrtf(d2);
                    float e2 = __builtin_amdgcn_exp2f(fmaf(c1, dist, SHIFT));
                    float e2t = (yj == ((ypack[mt] >> (8 * rr)) & 255)) ? e2 : 0.0f;
                    ts[mt][rr] += e2t;
                    bs[mt][rr] += e2;
                    jt += e2t;
                    jb += e2;
                }
            // col-side: reduce over the 4 kq groups; each (wv,col) written once
            jt += __shfl_xor(jt, 16, 64); jt += __shfl_xor(jt, 32, 64);
            jb += __shfl_xor(jb, 16, 64); jb += __shfl_xor(jb, 32, 64);
            if (kq == 0) {
                s_jt[wv][nt * 16 + mrow] = jt;
                s_jb[wv][nt * 16 + mrow] = jb;
            }
        }
    } else {
        // diagonal square half (64/1056 blocks): one-sided, guard i==j
        #pragma unroll 2
        for (int nt = 0; nt < NTJ; nt++) {
            LOAD_B_LDS(nt)
            const float sqj = s_sqj[nt * 16 + mrow];
            const int   yj  = s_yj[nt * 16 + mrow];
            const int   j   = J0 + nt * 16 + mrow;
            DO_MFMA()
            #pragma unroll
            for (int mt = 0; mt < 4; mt++)
                #pragma unroll
                for (int rr = 0; rr < 4; rr++) {
                    int i = iw + mt * 16 + kq * 4 + rr;
                    float d2 = fmaf(-2.0f, acc[mt][rr], sqi[mt][rr] + sqj);
                    d2 = fmaxf(d2, 0.0f);
                    float dist = __builtin_amdgcn_sqrtf(d2);
                    float e2 = __builtin_amdgcn_exp2f(fmaf(c1, dist, SHIFT));
                    bool offd = (i != j);
                    bool same = offd && (yj == ((ypack[mt] >> (8 * rr)) & 255));
                    bs[mt][rr] += offd ? e2 : 0.0f;
                    ts[mt][rr] += same ? e2 : 0.0f;
                }
        }
    }
#undef DO_MFMA
#undef LOAD_B_LDS

    // row-side: reduce across the 16 mrow lanes sharing each row, one atomic/row
    #pragma unroll
    for (int mt = 0; mt < 4; mt++)
        #pragma unroll
        for (int rr = 0; rr < 4; rr++) {
            float tv = ts[mt][rr], bv = bs[mt][rr];
            #pragma unroll
            for (int off = 1; off < 16; off <<= 1) {
                tv += __shfl_xor(tv, off, 64);
                bv += __shfl_xor(bv, off, 64);
            }
            if (mrow == 0) {
                int i = iw + mt * 16 + kq * 4 + rr;
                atomicAdd(&top[i], tv);
                atomicAdd(&bot[i], bv);
            }
        }

    // col-side drain: sum the 4 per-wave slices, one atomic per column
    if (!diag) {
        __syncthreads();
        if (tid < TILE_J) {
            float t = s_jt[0][tid] + s_jt[1][tid] + s_jt[2][tid] + s_jt[3][tid];
            float b = s_jb[0][tid] + s_jb[1][tid] + s_jb[2][tid] + s_jb[3][tid];
            atomicAdd(&top[J0 + tid], t);
            atomicAdd(&bot[J0 + tid], b);
        }
    }

    // fused finalization: last block to finish computes the loss
    __threadfence();
    __syncthreads();
    if (tid == 0) s_last = (atomicAdd(&g_ctr, 1u) == TB - 1);
    __syncthreads();
    if (s_last) {
        float acc = 0.0f;
        for (int r2 = tid; r2 < N_ROWS; r2 += 256) {
            float t = __hip_atomic_load(&top[r2], __ATOMIC_RELAXED, __HIP_MEMORY_SCOPE_AGENT);
            float b = __hip_atomic_load(&bot[r2], __ATOMIC_RELAXED, __HIP_MEMORY_SCOPE_AGENT);
            acc += (logf(t) - SHIFT_LN) - logf(b * 0x1p-64f + EPS);
        }
        #pragma unroll
        for (int off = 32; off > 0; off >>= 1) acc += __shfl_xor(acc, off, 64);
        if ((tid & 63) == 0) s_red[tid >> 6] = acc;
        __syncthreads();
        if (tid == 0)
            out[0] = -(s_red[0] + s_red[1] + s_red[2] + s_red[3]) / (float)N_ROWS;
    }
}

extern "C" void kernel_launch(void* const* d_in, const int* in_sizes, int n_in,
                              void* d_out, int out_size, void* d_ws, size_t ws_size,
                              hipStream_t stream) {
    const float* x = (const float*)d_in[0];
    const int*   y = (const int*)d_in[1];
    const float* w = (const float*)d_in[2];
    float* out = (float*)d_out;

    float* ws  = (float*)d_ws;
    float* top = ws;
    float* bot = ws + N_ROWS;
    float* sq  = ws + 2 * N_ROWS;
    _Float16* xh = (_Float16*)(ws + 3 * N_ROWS);
    _Float16* xl = xh + (size_t)N_ROWS * DIM;

    snn_prep<<<N_ROWS / 4, 256, 0, stream>>>(x, xh, xl, sq, top, bot, out);
    snn_mfma<<<TB, 256, 0, stream>>>(xh, xl, sq, y, w, top, bot, out);
}

// Round 7
// 129.799 us; speedup vs baseline: 2.0764x; 1.2599x over previous
//
#include <hip/hip_runtime.h>

typedef _Float16 f16x8 __attribute__((ext_vector_type(8)));
typedef float    f32x4 __attribute__((ext_vector_type(4)));

#define N_ROWS 8192
#define DIM 64
#define EPS 1e-8f
#define LOG2E 1.4426950408889634f
#define SHIFT 64.0f                      // exp terms scaled by 2^64
#define SHIFT_LN 44.361419555836499802f  // 64 * ln(2)
#define TILE 256                         // 256x256 pair tiles (4 waves, mt=4)
#define NBI (N_ROWS / TILE)              // 32 tiles per side
#define OFFB (NBI * (NBI - 1) / 2)       // 496 off-diagonal tiles (both-sided)
#define TB (OFFB + 2 * NBI)              // + 64 diagonal half-blocks = 560

// ws: top[8192] | bot[8192] | sq[8192] (f32) | xh[8192*64] | xl[8192*64] (f16)

// fused: zero top/bot/out + f16 split + row norms. one wave per row.
__global__ void snn_prep(const float* __restrict__ x, _Float16* __restrict__ xh,
                         _Float16* __restrict__ xl, float* __restrict__ sq,
                         float* __restrict__ top, float* __restrict__ bot,
                         float* __restrict__ out) {
    const int gt = blockIdx.x * 256 + threadIdx.x;
    if (gt < N_ROWS) { top[gt] = 0.0f; bot[gt] = 0.0f; }
    if (gt == 0) out[0] = 0.0f;
    const int row = gt >> 6, lane = threadIdx.x & 63;
    float v = x[row * DIM + lane];
    _Float16 h = (_Float16)v;
    _Float16 l = (_Float16)(v - (float)h);
    xh[row * DIM + lane] = h;
    xl[row * DIM + lane] = l;
    float s = v * v;
    #pragma unroll
    for (int off = 32; off > 0; off >>= 1) s += __shfl_xor(s, off, 64);
    if (lane == 0) sq[row] = s;
}

// Symmetric pass in the R0 block shape (the only structure measured at
// 2565 cyc/nt-slot; every shorter-loop / pipelined variant ran 4580-8000):
//  - 256x256 off-diag tiles, 16-nt plain loop, global B-loads, no pragmas
//  - both-sided accumulation (row-i in regs, col-j via per-wave LDS slices)
//  - 32 diagonal tiles split into 64 one-sided 8-nt HALF blocks, scheduled
//    last so scheduling stragglers are the short blocks
//  - __builtin_amdgcn_exp2f kept (R5/R6 proved -25% VALU); fused
//    finalization dropped (suspect in R5/R6 regressions, worth <2us)
__global__ __launch_bounds__(256, 2) void snn_mfma(
    const _Float16* __restrict__ xh, const _Float16* __restrict__ xl,
    const float* __restrict__ sq, const int* __restrict__ y,
    const float* __restrict__ w,
    float* __restrict__ top, float* __restrict__ bot)
{
    __shared__ float s_sqj[TILE];
    __shared__ int   s_yj[TILE];
    __shared__ float s_jt[4][TILE];   // per-wave col-side top (no atomics)
    __shared__ float s_jb[4][TILE];   // per-wave col-side bot

    const int bid = blockIdx.x;
    const bool diag = (bid >= OFFB);

    int bi, I0, J0, NT;
    if (!diag) {
        // off-diag: bid -> (bi, bj), bi in 1..31, bj < bi; cum before bi = bi(bi-1)/2
        bi = (int)((1.0f + sqrtf(8.0f * (float)bid + 1.0f)) * 0.5f);
        while (bi * (bi - 1) / 2 > bid) --bi;           // fp guards
        while ((bi + 1) * bi / 2 <= bid) ++bi;
        const int bj = bid - bi * (bi - 1) / 2;
        I0 = bi * TILE; J0 = bj * TILE; NT = 16;
    } else {
        const int t = bid - OFFB;                        // 0..63
        bi = t >> 1;
        I0 = bi * TILE; J0 = bi * TILE + (t & 1) * 128; NT = 8;
    }

    const int tid = threadIdx.x, wv = tid >> 6, lane = tid & 63;
    const int mrow = lane & 15, kq = lane >> 4;

    if (tid < NT * 16) {
        s_sqj[tid] = sq[J0 + tid];
        s_yj[tid]  = y[J0 + tid];
    }
    __syncthreads();

    const int iw = I0 + wv * 64;   // this wave's first i-row

    // A fragments resident for the block lifetime
    f16x8 ah[4][2], al[4][2];
    #pragma unroll
    for (int mt = 0; mt < 4; mt++)
        #pragma unroll
        for (int kc = 0; kc < 2; kc++) {
            int a = (iw + mt * 16 + mrow) * DIM + kc * 32 + kq * 8;
            ah[mt][kc] = *(const f16x8*)(xh + a);
            al[mt][kc] = *(const f16x8*)(xl + a);
        }

    // per-slot row metadata: i = iw + mt*16 + kq*4 + rr ; labels packed 4/VGPR
    float sqi[4][4]; int ypack[4];
    #pragma unroll
    for (int mt = 0; mt < 4; mt++) {
        int yp = 0;
        #pragma unroll
        for (int rr = 0; rr < 4; rr++) {
            int i = iw + mt * 16 + kq * 4 + rr;
            sqi[mt][rr] = sq[i];
            yp |= (y[i] & 255) << (8 * rr);
        }
        ypack[mt] = yp;
    }

    float ts[4][4], bs[4][4];
    #pragma unroll
    for (int mt = 0; mt < 4; mt++)
        #pragma unroll
        for (int rr = 0; rr < 4; rr++) { ts[mt][rr] = 0.0f; bs[mt][rr] = 0.0f; }

    const float c1 = -w[0] * LOG2E;

#define LOAD_B_AND_MFMA()                                                        \
    const int boff = (J0 + nt * 16 + mrow) * DIM + kq * 8;                       \
    f16x8 cbh0 = *(const f16x8*)(xh + boff);                                     \
    f16x8 cbh1 = *(const f16x8*)(xh + boff + 32);                                \
    f16x8 cbl0 = *(const f16x8*)(xl + boff);                                     \
    f16x8 cbl1 = *(const f16x8*)(xl + boff + 32);                                \
    const float sqj = s_sqj[nt * 16 + mrow];                                     \
    const int   yj  = s_yj[nt * 16 + mrow];                                      \
    f32x4 acc[4];                                                                \
    _Pragma("unroll")                                                            \
    for (int mt = 0; mt < 4; mt++) acc[mt] = (f32x4){0.f, 0.f, 0.f, 0.f};        \
    _Pragma("unroll")                                                            \
    for (int mt = 0; mt < 4; mt++)                                               \
        acc[mt] = __builtin_amdgcn_mfma_f32_16x16x32_f16(ah[mt][0], cbh0, acc[mt], 0, 0, 0); \
    _Pragma("unroll")                                                            \
    for (int mt = 0; mt < 4; mt++)                                               \
        acc[mt] = __builtin_amdgcn_mfma_f32_16x16x32_f16(ah[mt][1], cbh1, acc[mt], 0, 0, 0); \
    _Pragma("unroll")                                                            \
    for (int mt = 0; mt < 4; mt++)                                               \
        acc[mt] = __builtin_amdgcn_mfma_f32_16x16x32_f16(ah[mt][0], cbl0, acc[mt], 0, 0, 0); \
    _Pragma("unroll")                                                            \
    for (int mt = 0; mt < 4; mt++)                                               \
        acc[mt] = __builtin_amdgcn_mfma_f32_16x16x32_f16(ah[mt][1], cbl1, acc[mt], 0, 0, 0); \
    _Pragma("unroll")                                                            \
    for (int mt = 0; mt < 4; mt++)                                               \
        acc[mt] = __builtin_amdgcn_mfma_f32_16x16x32_f16(al[mt][0], cbh0, acc[mt], 0, 0, 0); \
    _Pragma("unroll")                                                            \
    for (int mt = 0; mt < 4; mt++)                                               \
        acc[mt] = __builtin_amdgcn_mfma_f32_16x16x32_f16(al[mt][1], cbh1, acc[mt], 0, 0, 0);

    if (!diag) {
        // off-diagonal: i != j guaranteed; accumulate both row-i and col-j sides
        for (int nt = 0; nt < 16; nt++) {
            LOAD_B_AND_MFMA()
            float jt = 0.0f, jb = 0.0f;
            #pragma unroll
            for (int mt = 0; mt < 4; mt++)
                #pragma unroll
                for (int rr = 0; rr < 4; rr++) {
                    float d2 = fmaf(-2.0f, acc[mt][rr], sqi[mt][rr] + sqj);
                    d2 = fmaxf(d2, 0.0f);
                    float dist = __builtin_amdgcn_sqrtf(d2);
                    float e2 = __builtin_amdgcn_exp2f(fmaf(c1, dist, SHIFT));
                    float e2t = (yj == ((ypack[mt] >> (8 * rr)) & 255)) ? e2 : 0.0f;
                    ts[mt][rr] += e2t;
                    bs[mt][rr] += e2;
                    jt += e2t;
                    jb += e2;
                }
            // col-side: reduce over the 4 kq groups; each (wv,col) written once
            jt += __shfl_xor(jt, 16, 64); jt += __shfl_xor(jt, 32, 64);
            jb += __shfl_xor(jb, 16, 64); jb += __shfl_xor(jb, 32, 64);
            if (kq == 0) {
                s_jt[wv][nt * 16 + mrow] = jt;
                s_jb[wv][nt * 16 + mrow] = jb;
            }
        }
    } else {
        // diagonal half-block: one-sided over 8 nt, guard i==j (both orders of
        // each in-tile pair are visited across the two half-blocks)
        for (int nt = 0; nt < 8; nt++) {
            LOAD_B_AND_MFMA()
            const int j = J0 + nt * 16 + mrow;
            #pragma unroll
            for (int mt = 0; mt < 4; mt++)
                #pragma unroll
                for (int rr = 0; rr < 4; rr++) {
                    int i = iw + mt * 16 + kq * 4 + rr;
                    float d2 = fmaf(-2.0f, acc[mt][rr], sqi[mt][rr] + sqj);
                    d2 = fmaxf(d2, 0.0f);
                    float dist = __builtin_amdgcn_sqrtf(d2);
                    float e2 = __builtin_amdgcn_exp2f(fmaf(c1, dist, SHIFT));
                    bool offd = (i != j);
                    bool same = offd && (yj == ((ypack[mt] >> (8 * rr)) & 255));
                    bs[mt][rr] += offd ? e2 : 0.0f;
                    ts[mt][rr] += same ? e2 : 0.0f;
                }
        }
    }
#undef LOAD_B_AND_MFMA

    // row-side: reduce across the 16 mrow lanes sharing each row, one atomic/row
    #pragma unroll
    for (int mt = 0; mt < 4; mt++)
        #pragma unroll
        for (int rr = 0; rr < 4; rr++) {
            float tv = ts[mt][rr], bv = bs[mt][rr];
            #pragma unroll
            for (int off = 1; off < 16; off <<= 1) {
                tv += __shfl_xor(tv, off, 64);
                bv += __shfl_xor(bv, off, 64);
            }
            if (mrow == 0) {
                int i = iw + mt * 16 + kq * 4 + rr;
                atomicAdd(&top[i], tv);
                atomicAdd(&bot[i], bv);
            }
        }

    // col-side drain: sum the 4 per-wave slices, one atomic per column
    if (!diag) {
        __syncthreads();
        float t = s_jt[0][tid] + s_jt[1][tid] + s_jt[2][tid] + s_jt[3][tid];
        float b = s_jb[0][tid] + s_jb[1][tid] + s_jb[2][tid] + s_jb[3][tid];
        atomicAdd(&top[J0 + tid], t);
        atomicAdd(&bot[J0 + tid], b);
    }
}

__global__ __launch_bounds__(256) void snn_final(
    const float* __restrict__ top, const float* __restrict__ bot,
    float* __restrict__ out)
{
    const int i = blockIdx.x * 256 + threadIdx.x;
    float t = top[i];                    // top * 2^64, normal fp32
    float b = bot[i] * 0x1p-64f + EPS;   // bot tiny; +eps dominates
    float acc = (logf(t) - SHIFT_LN) - logf(b);
    #pragma unroll
    for (int off = 32; off > 0; off >>= 1) acc += __shfl_xor(acc, off, 64);
    __shared__ float red[4];
    if ((threadIdx.x & 63) == 0) red[threadIdx.x >> 6] = acc;
    __syncthreads();
    if (threadIdx.x == 0) {
        float s = red[0] + red[1] + red[2] + red[3];
        atomicAdd(out, -s / (float)N_ROWS);
    }
}

extern "C" void kernel_launch(void* const* d_in, const int* in_sizes, int n_in,
                              void* d_out, int out_size, void* d_ws, size_t ws_size,
                              hipStream_t stream) {
    const float* x = (const float*)d_in[0];
    const int*   y = (const int*)d_in[1];
    const float* w = (const float*)d_in[2];
    float* out = (float*)d_out;

    float* ws  = (float*)d_ws;
    float* top = ws;
    float* bot = ws + N_ROWS;
    float* sq  = ws + 2 * N_ROWS;
    _Float16* xh = (_Float16*)(ws + 3 * N_ROWS);
    _Float16* xl = xh + (size_t)N_ROWS * DIM;

    snn_prep<<<N_ROWS / 4, 256, 0, stream>>>(x, xh, xl, sq, top, bot, out);
    snn_mfma<<<TB, 256, 0, stream>>>(xh, xl, sq, y, w, top, bot);
    snn_final<<<N_ROWS / 256, 256, 0, stream>>>(top, bot, out);
}

// Round 8
// 97.452 us; speedup vs baseline: 2.7656x; 1.3319x over previous
//
#include <hip/hip_runtime.h>

typedef _Float16 f16x8 __attribute__((ext_vector_type(8)));
typedef float    f32x4 __attribute__((ext_vector_type(4)));

#define N_ROWS 8192
#define DIM 64
#define EPS 1e-8f
#define LOG2E 1.4426950408889634f
#define SHIFT 64.0f                      // exp terms scaled by 2^64
#define SHIFT_LN 44.361419555836499802f  // 64 * ln(2)
#define TILE_I 256                       // i-panel (4 waves x 64 rows, mt=4)
#define NBI (N_ROWS / TILE_I)            // 32 panels
#define TB 512                           // EXACTLY one block per CU slot
#define MAXC 17                          // max j-chunks (16 rows each) per block

// ws: top[8192] | bot[8192] | sq[8192] (f32) | xh[8192*64] | xl[8192*64] (f16)

// fused: zero top/bot/out + f16 split + row norms. one wave per row.
__global__ void snn_prep(const float* __restrict__ x, _Float16* __restrict__ xh,
                         _Float16* __restrict__ xl, float* __restrict__ sq,
                         float* __restrict__ top, float* __restrict__ bot,
                         float* __restrict__ out) {
    const int gt = blockIdx.x * 256 + threadIdx.x;
    if (gt < N_ROWS) { top[gt] = 0.0f; bot[gt] = 0.0f; }
    if (gt == 0) out[0] = 0.0f;
    const int row = gt >> 6, lane = threadIdx.x & 63;
    float v = x[row * DIM + lane];
    _Float16 h = (_Float16)v;
    _Float16 l = (_Float16)(v - (float)h);
    xh[row * DIM + lane] = h;
    xl[row * DIM + lane] = l;
    float s = v * v;
    #pragma unroll
    for (int off = 32; off > 0; off >>= 1) s += __shfl_xor(s, off, 64);
    if (lane == 0) sq[row] = s;
}

// Symmetric triangular pass, re-partitioned into EXACTLY 512 uniform blocks.
// Seven-round model: T = ceil(blocks/512) * NT/block * t_nt fits R0/R1/R2/R7
// within 2% (t_nt ~= 2.3us w/ builtin exp2); all regressions were partial
// scheduling rounds. This grid: 512 blocks of 16-17 j-chunks (16 rows each),
// contiguous within one i-panel (A-frags stay resident):
//   panels 0..15 : (bi+1) blocks x 16 chunks          = 136 blocks
//   panels 16..31: 16 x 17-chunk + (bi-16) x 16-chunk = 376 blocks
//   total 256x17 + 256x16 = 8448 chunks, 512 blocks -> ONE round, no tail.
// Diagonal chunks (jc >= 16*bi, always the range tail) use the one-sided
// i!=j body; sub-diagonal chunks accumulate both row-i and col-j sides.
__global__ __launch_bounds__(256, 2) void snn_mfma(
    const _Float16* __restrict__ xh, const _Float16* __restrict__ xl,
    const float* __restrict__ sq, const int* __restrict__ y,
    const float* __restrict__ w,
    float* __restrict__ top, float* __restrict__ bot)
{
    __shared__ float s_sqj[MAXC * 16];
    __shared__ int   s_yj[MAXC * 16];
    __shared__ float s_jt[4][MAXC * 16];   // per-wave col-side top (no atomics)
    __shared__ float s_jb[4][MAXC * 16];   // per-wave col-side bot

    // ---- decode bid -> (panel bi, chunk range [c0, c0+len)) ----
    const int bid = blockIdx.x;
    int bi = 0, kk = 0, cum = 0;
    for (int p = 0; p < NBI; p++) {
        int nb = (p < 16) ? p + 1 : p;          // blocks in panel p
        if (bid < cum + nb) { bi = p; kk = bid - cum; break; }
        cum += nb;
    }
    int c0, len;
    if (bi < 16)      { c0 = 16 * kk;            len = 16; }
    else if (kk < 16) { c0 = 17 * kk;            len = 17; }
    else              { c0 = 272 + 16 * (kk - 16); len = 16; }
    const int ndch = min(max(16 * bi - c0, 0), len);  // leading non-diag chunks
    const int I0 = bi * TILE_I;

    const int tid = threadIdx.x, wv = tid >> 6, lane = tid & 63;
    const int mrow = lane & 15, kq = lane >> 4;

    for (int t = tid; t < len * 16; t += 256) {
        s_sqj[t] = sq[c0 * 16 + t];
        s_yj[t]  = y[c0 * 16 + t];
    }
    __syncthreads();

    const int iw = I0 + wv * 64;   // this wave's first i-row

    // A fragments resident for the block lifetime
    f16x8 ah[4][2], al[4][2];
    #pragma unroll
    for (int mt = 0; mt < 4; mt++)
        #pragma unroll
        for (int kc = 0; kc < 2; kc++) {
            int a = (iw + mt * 16 + mrow) * DIM + kc * 32 + kq * 8;
            ah[mt][kc] = *(const f16x8*)(xh + a);
            al[mt][kc] = *(const f16x8*)(xl + a);
        }

    // per-slot row metadata: i = iw + mt*16 + kq*4 + rr ; labels packed 4/VGPR
    float sqi[4][4]; int ypack[4];
    #pragma unroll
    for (int mt = 0; mt < 4; mt++) {
        int yp = 0;
        #pragma unroll
        for (int rr = 0; rr < 4; rr++) {
            int i = iw + mt * 16 + kq * 4 + rr;
            sqi[mt][rr] = sq[i];
            yp |= (y[i] & 255) << (8 * rr);
        }
        ypack[mt] = yp;
    }

    float ts[4][4], bs[4][4];
    #pragma unroll
    for (int mt = 0; mt < 4; mt++)
        #pragma unroll
        for (int rr = 0; rr < 4; rr++) { ts[mt][rr] = 0.0f; bs[mt][rr] = 0.0f; }

    const float c1 = -w[0] * LOG2E;

#define LOAD_B_AND_MFMA()                                                        \
    const int jr = (c0 + ntl) * 16 + mrow;        /* this lane's global j row */ \
    const int boff = jr * DIM + kq * 8;                                          \
    f16x8 cbh0 = *(const f16x8*)(xh + boff);                                     \
    f16x8 cbh1 = *(const f16x8*)(xh + boff + 32);                                \
    f16x8 cbl0 = *(const f16x8*)(xl + boff);                                     \
    f16x8 cbl1 = *(const f16x8*)(xl + boff + 32);                                \
    const float sqj = s_sqj[ntl * 16 + mrow];                                    \
    const int   yj  = s_yj[ntl * 16 + mrow];                                     \
    f32x4 acc[4];                                                                \
    _Pragma("unroll")                                                            \
    for (int mt = 0; mt < 4; mt++) acc[mt] = (f32x4){0.f, 0.f, 0.f, 0.f};        \
    _Pragma("unroll")                                                            \
    for (int mt = 0; mt < 4; mt++)                                               \
        acc[mt] = __builtin_amdgcn_mfma_f32_16x16x32_f16(ah[mt][0], cbh0, acc[mt], 0, 0, 0); \
    _Pragma("unroll")                                                            \
    for (int mt = 0; mt < 4; mt++)                                               \
        acc[mt] = __builtin_amdgcn_mfma_f32_16x16x32_f16(ah[mt][1], cbh1, acc[mt], 0, 0, 0); \
    _Pragma("unroll")                                                            \
    for (int mt = 0; mt < 4; mt++)                                               \
        acc[mt] = __builtin_amdgcn_mfma_f32_16x16x32_f16(ah[mt][0], cbl0, acc[mt], 0, 0, 0); \
    _Pragma("unroll")                                                            \
    for (int mt = 0; mt < 4; mt++)                                               \
        acc[mt] = __builtin_amdgcn_mfma_f32_16x16x32_f16(ah[mt][1], cbl1, acc[mt], 0, 0, 0); \
    _Pragma("unroll")                                                            \
    for (int mt = 0; mt < 4; mt++)                                               \
        acc[mt] = __builtin_amdgcn_mfma_f32_16x16x32_f16(al[mt][0], cbh0, acc[mt], 0, 0, 0); \
    _Pragma("unroll")                                                            \
    for (int mt = 0; mt < 4; mt++)                                               \
        acc[mt] = __builtin_amdgcn_mfma_f32_16x16x32_f16(al[mt][1], cbh1, acc[mt], 0, 0, 0);

    // ---- loop 1: sub-diagonal chunks, both-sided, i != j guaranteed ----
    for (int ntl = 0; ntl < ndch; ntl++) {
        LOAD_B_AND_MFMA()
        float jt = 0.0f, jb = 0.0f;
        #pragma unroll
        for (int mt = 0; mt < 4; mt++)
            #pragma unroll
            for (int rr = 0; rr < 4; rr++) {
                float d2 = fmaf(-2.0f, acc[mt][rr], sqi[mt][rr] + sqj);
                d2 = fmaxf(d2, 0.0f);
                float dist = __builtin_amdgcn_sqrtf(d2);
                float e2 = __builtin_amdgcn_exp2f(fmaf(c1, dist, SHIFT));
                float e2t = (yj == ((ypack[mt] >> (8 * rr)) & 255)) ? e2 : 0.0f;
                ts[mt][rr] += e2t;
                bs[mt][rr] += e2;
                jt += e2t;
                jb += e2;
            }
        // col-side: reduce over the 4 kq groups; each (wv,col) written once
        jt += __shfl_xor(jt, 16, 64); jt += __shfl_xor(jt, 32, 64);
        jb += __shfl_xor(jb, 16, 64); jb += __shfl_xor(jb, 32, 64);
        if (kq == 0) {
            s_jt[wv][ntl * 16 + mrow] = jt;
            s_jb[wv][ntl * 16 + mrow] = jb;
        }
    }

    // ---- loop 2: diagonal chunks (range tail), one-sided, guard i==j ----
    for (int ntl = ndch; ntl < len; ntl++) {
        LOAD_B_AND_MFMA()
        #pragma unroll
        for (int mt = 0; mt < 4; mt++)
            #pragma unroll
            for (int rr = 0; rr < 4; rr++) {
                int i = iw + mt * 16 + kq * 4 + rr;
                float d2 = fmaf(-2.0f, acc[mt][rr], sqi[mt][rr] + sqj);
                d2 = fmaxf(d2, 0.0f);
                float dist = __builtin_amdgcn_sqrtf(d2);
                float e2 = __builtin_amdgcn_exp2f(fmaf(c1, dist, SHIFT));
                bool offd = (i != jr);
                bool same = offd && (yj == ((ypack[mt] >> (8 * rr)) & 255));
                bs[mt][rr] += offd ? e2 : 0.0f;
                ts[mt][rr] += same ? e2 : 0.0f;
            }
    }
#undef LOAD_B_AND_MFMA

    // row-side: reduce across the 16 mrow lanes sharing each row, one atomic/row
    #pragma unroll
    for (int mt = 0; mt < 4; mt++)
        #pragma unroll
        for (int rr = 0; rr < 4; rr++) {
            float tv = ts[mt][rr], bv = bs[mt][rr];
            #pragma unroll
            for (int off = 1; off < 16; off <<= 1) {
                tv += __shfl_xor(tv, off, 64);
                bv += __shfl_xor(bv, off, 64);
            }
            if (mrow == 0) {
                int i = iw + mt * 16 + kq * 4 + rr;
                atomicAdd(&top[i], tv);
                atomicAdd(&bot[i], bv);
            }
        }

    // col-side drain: sum the 4 per-wave slices, one atomic per column
    if (ndch > 0) {                         // block-uniform condition
        __syncthreads();
        for (int t = tid; t < ndch * 16; t += 256) {
            float tt = s_jt[0][t] + s_jt[1][t] + s_jt[2][t] + s_jt[3][t];
            float bb = s_jb[0][t] + s_jb[1][t] + s_jb[2][t] + s_jb[3][t];
            atomicAdd(&top[c0 * 16 + t], tt);
            atomicAdd(&bot[c0 * 16 + t], bb);
        }
    }
}

__global__ __launch_bounds__(256) void snn_final(
    const float* __restrict__ top, const float* __restrict__ bot,
    float* __restrict__ out)
{
    const int i = blockIdx.x * 256 + threadIdx.x;
    float t = top[i];                    // top * 2^64, normal fp32
    float b = bot[i] * 0x1p-64f + EPS;   // bot tiny; +eps dominates
    float acc = (logf(t) - SHIFT_LN) - logf(b);
    #pragma unroll
    for (int off = 32; off > 0; off >>= 1) acc += __shfl_xor(acc, off, 64);
    __shared__ float red[4];
    if ((threadIdx.x & 63) == 0) red[threadIdx.x >> 6] = acc;
    __syncthreads();
    if (threadIdx.x == 0) {
        float s = red[0] + red[1] + red[2] + red[3];
        atomicAdd(out, -s / (float)N_ROWS);
    }
}

extern "C" void kernel_launch(void* const* d_in, const int* in_sizes, int n_in,
                              void* d_out, int out_size, void* d_ws, size_t ws_size,
                              hipStream_t stream) {
    const float* x = (const float*)d_in[0];
    const int*   y = (const int*)d_in[1];
    const float* w = (const float*)d_in[2];
    float* out = (float*)d_out;

    float* ws  = (float*)d_ws;
    float* top = ws;
    float* bot = ws + N_ROWS;
    float* sq  = ws + 2 * N_ROWS;
    _Float16* xh = (_Float16*)(ws + 3 * N_ROWS);
    _Float16* xl = xh + (size_t)N_ROWS * DIM;

    snn_prep<<<N_ROWS / 4, 256, 0, stream>>>(x, xh, xl, sq, top, bot, out);
    snn_mfma<<<TB, 256, 0, stream>>>(xh, xl, sq, y, w, top, bot);
    snn_final<<<N_ROWS / 256, 256, 0, stream>>>(top, bot, out);
}